// Round 1
// baseline (329.707 us; speedup 1.0000x reference)
//
#include <hip/hip_runtime.h>

// ---------------------------------------------------------------------------
// MultiHeadAttention (B=2, T=2048, D=1024, NH=16, hd=64) with ALiBi + causal.
// Pipeline: fp32->bf16 convert | fused QKV MFMA GEMM | flash attention | out GEMM.
// All MFMA GEMMs in NT form with identical A/B per-lane addressing so the
// (undocumented) A/B k-lane mapping cancels; only the verified C/D layout
// (col=lane&15, row=(lane>>4)*4+reg) is relied upon.
// ---------------------------------------------------------------------------

using f32x4  = __attribute__((ext_vector_type(4))) float;
using bf16x8 = __attribute__((ext_vector_type(8))) short;
typedef unsigned short u16;
using u16x4 = __attribute__((ext_vector_type(4))) u16;

#define T_SEQ  2048
#define NHEAD  16
#define HDIM   64
#define DMODEL 1024
#define MROWS  4096   // B*T

__device__ __forceinline__ u16 f2bf(float f) {
  union { float f; unsigned u; } v; v.f = f;
  return (u16)((v.u + 0x7fffu + ((v.u >> 16) & 1u)) >> 16);  // RNE
}

// ---------------------------------------------------------------------------
__global__ __launch_bounds__(256) void cvt_bf16(const float* __restrict__ src,
                                                u16* __restrict__ dst, int n) {
  int i = (blockIdx.x * 256 + threadIdx.x) * 4;
  if (i < n) {
    const float4 v = *reinterpret_cast<const float4*>(src + i);
    u16x4 o;
    o.x = f2bf(v.x); o.y = f2bf(v.y); o.z = f2bf(v.z); o.w = f2bf(v.w);
    *reinterpret_cast<u16x4*>(dst + i) = o;
  }
}

// ---------------------------------------------------------------------------
// Fused QKV projection: Y = x @ W^T + b   (M=4096, N=1024, K=1024), bf16 MFMA.
// z = blockIdx.z selects {Q,K,V}. Q,K scaled by D^-0.25. V stored transposed.
// 128x128 tile, 4 waves (2x2), each wave 64x64 (4x4 frags of 16x16), BK=64.
__global__ __launch_bounds__(256) void qkv_gemm(
    const u16* __restrict__ xb,
    const u16* __restrict__ wq, const u16* __restrict__ wk, const u16* __restrict__ wv,
    const float* __restrict__ bq, const float* __restrict__ bk, const float* __restrict__ bv,
    u16* __restrict__ q_ws, u16* __restrict__ k_ws, u16* __restrict__ vt_ws)
{
  const int K = DMODEL;
  const int z = blockIdx.z;
  const u16*  W    = (z == 0) ? wq : (z == 1) ? wk : wv;
  const float* bias = (z == 0) ? bq : (z == 1) ? bk : bv;
  const int bm = blockIdx.y, bn = blockIdx.x;
  const int tid = threadIdx.x;
  const int w = tid >> 6, lane = tid & 63, g = lane >> 4, c = lane & 15;
  const int wm = w >> 1, wn = w & 1;

  __shared__ u16 As[128][72];  // 64 + 8 pad: breaks bank-conflict stride
  __shared__ u16 Bs[128][72];

  f32x4 zero4 = {0.f, 0.f, 0.f, 0.f};
  f32x4 acc[4][4];
#pragma unroll
  for (int m = 0; m < 4; ++m)
#pragma unroll
    for (int n = 0; n < 4; ++n) acc[m][n] = zero4;

  for (int k0 = 0; k0 < K; k0 += 64) {
#pragma unroll
    for (int j = 0; j < 4; ++j) {
      int chunk = tid + 256 * j;          // 1024 chunks of 8 bf16
      int r  = chunk >> 3;
      int cc = (chunk & 7) * 8;
      *reinterpret_cast<bf16x8*>(&As[r][cc]) =
          *reinterpret_cast<const bf16x8*>(xb + (size_t)(bm * 128 + r) * K + k0 + cc);
      *reinterpret_cast<bf16x8*>(&Bs[r][cc]) =
          *reinterpret_cast<const bf16x8*>(W + (size_t)(bn * 128 + r) * K + k0 + cc);
    }
    __syncthreads();
#pragma unroll
    for (int kk = 0; kk < 2; ++kk) {
      bf16x8 af[4], bfr[4];
#pragma unroll
      for (int m = 0; m < 4; ++m)
        af[m] = *reinterpret_cast<const bf16x8*>(&As[wm * 64 + m * 16 + c][kk * 32 + g * 8]);
#pragma unroll
      for (int n = 0; n < 4; ++n)
        bfr[n] = *reinterpret_cast<const bf16x8*>(&Bs[wn * 64 + n * 16 + c][kk * 32 + g * 8]);
#pragma unroll
      for (int m = 0; m < 4; ++m)
#pragma unroll
        for (int n = 0; n < 4; ++n)
          acc[m][n] = __builtin_amdgcn_mfma_f32_16x16x32_bf16(af[m], bfr[n], acc[m][n], 0, 0, 0);
    }
    __syncthreads();
  }

  const float rs = 0.1767766953f;  // 1024^-0.25
#pragma unroll
  for (int m = 0; m < 4; ++m) {
    int mrow_base = bm * 128 + wm * 64 + m * 16 + g * 4;
#pragma unroll
    for (int n = 0; n < 4; ++n) {
      int n_idx = bn * 128 + wn * 64 + n * 16 + c;
      float bv_ = bias[n_idx];
      int h = n_idx >> 6, d = n_idx & 63;
#pragma unroll
      for (int i = 0; i < 4; ++i) {
        int mrow = mrow_base + i;
        int b = mrow >> 11, t = mrow & (T_SEQ - 1);
        float val = acc[m][n][i] + bv_;
        if (z < 2) val *= rs;
        u16 ov = f2bf(val);
        if (z == 0)      q_ws[((size_t)(b * NHEAD + h) * T_SEQ + t) * HDIM + d] = ov;
        else if (z == 1) k_ws[((size_t)(b * NHEAD + h) * T_SEQ + t) * HDIM + d] = ov;
        else             vt_ws[((size_t)(b * NHEAD + h) * HDIM + d) * T_SEQ + t] = ov;
      }
    }
  }
}

// ---------------------------------------------------------------------------
// Flash attention with ALiBi + causal. Grid (T/64, B*NH), 4 waves/block,
// each wave owns 16 q-rows. KV tiles of 64, online softmax in fp32.
__global__ __launch_bounds__(256) void attn_fused(
    const u16* __restrict__ Q, const u16* __restrict__ Kt,
    const u16* __restrict__ VT, u16* __restrict__ O)
{
  const int w = threadIdx.x >> 6;
  const int lane = threadIdx.x & 63;
  const int g = lane >> 4;
  const int c = lane & 15;
  const int q0 = blockIdx.x * 64;
  const int bh = blockIdx.y;
  const int h = bh & (NHEAD - 1);
  const int b = bh >> 4;
  const float slope = exp2f(-0.5f * (float)(h + 1));  // 2^(-8(h+1)/16)
  const u16* Qp = Q  + (size_t)bh * T_SEQ * HDIM;
  const u16* Kp = Kt + (size_t)bh * T_SEQ * HDIM;
  const u16* Vp = VT + (size_t)bh * HDIM * T_SEQ;
  const int qrow = q0 + w * 16;

  bf16x8 qf[2];
  qf[0] = *reinterpret_cast<const bf16x8*>(Qp + (size_t)(qrow + c) * HDIM + g * 8);
  qf[1] = *reinterpret_cast<const bf16x8*>(Qp + (size_t)(qrow + c) * HDIM + 32 + g * 8);

  f32x4 zero4 = {0.f, 0.f, 0.f, 0.f};
  f32x4 o[4];
  float mrun[4], lrun[4];
#pragma unroll
  for (int i = 0; i < 4; ++i) { mrun[i] = -1e30f; lrun[i] = 0.f; }
#pragma unroll
  for (int dg = 0; dg < 4; ++dg) o[dg] = zero4;

  __shared__ u16 P[4][16][72];  // per-wave P tile [16 q][64 kv], +8 pad

  for (int kv0 = 0; kv0 <= q0; kv0 += 64) {
    f32x4 s[4];
#pragma unroll
    for (int jj = 0; jj < 4; ++jj) {
      const u16* kr = Kp + (size_t)(kv0 + jj * 16 + c) * HDIM;
      bf16x8 k0 = *reinterpret_cast<const bf16x8*>(kr + g * 8);
      bf16x8 k1 = *reinterpret_cast<const bf16x8*>(kr + 32 + g * 8);
      f32x4 zacc = zero4;
      zacc = __builtin_amdgcn_mfma_f32_16x16x32_bf16(qf[0], k0, zacc, 0, 0, 0);
      zacc = __builtin_amdgcn_mfma_f32_16x16x32_bf16(qf[1], k1, zacc, 0, 0, 0);
      s[jj] = zacc;
    }

    const bool edge = (kv0 == q0);  // only tile where kv can exceed q
    float mx[4];
#pragma unroll
    for (int i = 0; i < 4; ++i) mx[i] = -1e30f;
#pragma unroll
    for (int jj = 0; jj < 4; ++jj) {
#pragma unroll
      for (int i = 0; i < 4; ++i) {
        int qi  = qrow + g * 4 + i;       // C/D row = (lane>>4)*4 + reg
        int kvi = kv0 + jj * 16 + c;      // C/D col = lane&15
        float sv = s[jj][i] + slope * (float)(kvi - qi);
        if (edge && kvi > qi) sv = -1e30f;
        s[jj][i] = sv;
        mx[i] = fmaxf(mx[i], sv);
      }
    }
#pragma unroll
    for (int i = 0; i < 4; ++i) {
      float v = mx[i];
      v = fmaxf(v, __shfl_xor(v, 1, 64));
      v = fmaxf(v, __shfl_xor(v, 2, 64));
      v = fmaxf(v, __shfl_xor(v, 4, 64));
      v = fmaxf(v, __shfl_xor(v, 8, 64));
      float mnew = fmaxf(mrun[i], v);
      float al = __expf(mrun[i] - mnew);
      mrun[i] = mnew;
      lrun[i] *= al;
#pragma unroll
      for (int dg = 0; dg < 4; ++dg) o[dg][i] *= al;
      mx[i] = 0.f;  // becomes row-sum accumulator
    }
#pragma unroll
    for (int jj = 0; jj < 4; ++jj) {
#pragma unroll
      for (int i = 0; i < 4; ++i) {
        float p = __expf(s[jj][i] - mrun[i]);
        mx[i] += p;
        P[w][g * 4 + i][jj * 16 + c] = f2bf(p);
      }
    }
#pragma unroll
    for (int i = 0; i < 4; ++i) {
      float v = mx[i];
      v += __shfl_xor(v, 1, 64);
      v += __shfl_xor(v, 2, 64);
      v += __shfl_xor(v, 4, 64);
      v += __shfl_xor(v, 8, 64);
      lrun[i] += v;
    }
    __syncthreads();  // drain LDS: P writes visible to all lanes of the wave

    bf16x8 pa0 = *reinterpret_cast<const bf16x8*>(&P[w][c][g * 8]);
    bf16x8 pa1 = *reinterpret_cast<const bf16x8*>(&P[w][c][32 + g * 8]);
#pragma unroll
    for (int dg = 0; dg < 4; ++dg) {
      const u16* vr = Vp + (size_t)(dg * 16 + c) * T_SEQ + kv0;
      bf16x8 v0 = *reinterpret_cast<const bf16x8*>(vr + g * 8);
      bf16x8 v1 = *reinterpret_cast<const bf16x8*>(vr + 32 + g * 8);
      o[dg] = __builtin_amdgcn_mfma_f32_16x16x32_bf16(pa0, v0, o[dg], 0, 0, 0);
      o[dg] = __builtin_amdgcn_mfma_f32_16x16x32_bf16(pa1, v1, o[dg], 0, 0, 0);
    }
    __syncthreads();  // P reads done before next iteration overwrites
  }

#pragma unroll
  for (int dg = 0; dg < 4; ++dg) {
#pragma unroll
    for (int i = 0; i < 4; ++i) {
      int qi = qrow + g * 4 + i;
      float val = o[dg][i] / lrun[i];
      O[((size_t)b * T_SEQ + qi) * DMODEL + h * HDIM + dg * 16 + c] = f2bf(val);
    }
  }
}

// ---------------------------------------------------------------------------
// Output projection: out = ao @ Wp^T + bp  (fp32 out). Same GEMM core.
__global__ __launch_bounds__(256) void out_gemm(
    const u16* __restrict__ ao, const u16* __restrict__ wp,
    const float* __restrict__ bp, float* __restrict__ out)
{
  const int K = DMODEL;
  const int bm = blockIdx.y, bn = blockIdx.x;
  const int tid = threadIdx.x;
  const int w = tid >> 6, lane = tid & 63, g = lane >> 4, c = lane & 15;
  const int wm = w >> 1, wn = w & 1;

  __shared__ u16 As[128][72];
  __shared__ u16 Bs[128][72];

  f32x4 zero4 = {0.f, 0.f, 0.f, 0.f};
  f32x4 acc[4][4];
#pragma unroll
  for (int m = 0; m < 4; ++m)
#pragma unroll
    for (int n = 0; n < 4; ++n) acc[m][n] = zero4;

  for (int k0 = 0; k0 < K; k0 += 64) {
#pragma unroll
    for (int j = 0; j < 4; ++j) {
      int chunk = tid + 256 * j;
      int r  = chunk >> 3;
      int cc = (chunk & 7) * 8;
      *reinterpret_cast<bf16x8*>(&As[r][cc]) =
          *reinterpret_cast<const bf16x8*>(ao + (size_t)(bm * 128 + r) * K + k0 + cc);
      *reinterpret_cast<bf16x8*>(&Bs[r][cc]) =
          *reinterpret_cast<const bf16x8*>(wp + (size_t)(bn * 128 + r) * K + k0 + cc);
    }
    __syncthreads();
#pragma unroll
    for (int kk = 0; kk < 2; ++kk) {
      bf16x8 af[4], bfr[4];
#pragma unroll
      for (int m = 0; m < 4; ++m)
        af[m] = *reinterpret_cast<const bf16x8*>(&As[wm * 64 + m * 16 + c][kk * 32 + g * 8]);
#pragma unroll
      for (int n = 0; n < 4; ++n)
        bfr[n] = *reinterpret_cast<const bf16x8*>(&Bs[wn * 64 + n * 16 + c][kk * 32 + g * 8]);
#pragma unroll
      for (int m = 0; m < 4; ++m)
#pragma unroll
        for (int n = 0; n < 4; ++n)
          acc[m][n] = __builtin_amdgcn_mfma_f32_16x16x32_bf16(af[m], bfr[n], acc[m][n], 0, 0, 0);
    }
    __syncthreads();
  }

#pragma unroll
  for (int m = 0; m < 4; ++m) {
    int mrow_base = bm * 128 + wm * 64 + m * 16 + g * 4;
#pragma unroll
    for (int n = 0; n < 4; ++n) {
      int n_idx = bn * 128 + wn * 64 + n * 16 + c;
      float bv_ = bp[n_idx];
#pragma unroll
      for (int i = 0; i < 4; ++i) {
        int mrow = mrow_base + i;
        out[(size_t)mrow * DMODEL + n_idx] = acc[m][n][i] + bv_;
      }
    }
  }
}

// ---------------------------------------------------------------------------
extern "C" void kernel_launch(void* const* d_in, const int* in_sizes, int n_in,
                              void* d_out, int out_size, void* d_ws, size_t ws_size,
                              hipStream_t stream) {
  const float* x  = (const float*)d_in[0];
  const float* Wq = (const float*)d_in[1];
  const float* bq = (const float*)d_in[2];
  const float* Wk = (const float*)d_in[3];
  const float* bk = (const float*)d_in[4];
  const float* Wv = (const float*)d_in[5];
  const float* bv = (const float*)d_in[6];
  const float* Wp = (const float*)d_in[7];
  const float* bp = (const float*)d_in[8];
  float* out = (float*)d_out;

  // workspace layout (u16 elements): 48 MB total
  u16* ws    = (u16*)d_ws;
  u16* xb    = ws;                       // 4,194,304  (x as bf16)
  u16* wqb   = xb   + 4194304;           // 1,048,576
  u16* wkb   = wqb  + 1048576;
  u16* wvb   = wkb  + 1048576;
  u16* wpb   = wvb  + 1048576;
  u16* q_ws  = wpb  + 1048576;           // [B,NH,T,hd]
  u16* k_ws  = q_ws + 4194304;           // [B,NH,T,hd]
  u16* vt_ws = k_ws + 4194304;           // [B,NH,hd,T]
  u16* ao    = vt_ws + 4194304;          // [B,T,D] attention output

  cvt_bf16<<<4096, 256, 0, stream>>>(x,  xb,  4194304);
  cvt_bf16<<<1024, 256, 0, stream>>>(Wq, wqb, 1048576);
  cvt_bf16<<<1024, 256, 0, stream>>>(Wk, wkb, 1048576);
  cvt_bf16<<<1024, 256, 0, stream>>>(Wv, wvb, 1048576);
  cvt_bf16<<<1024, 256, 0, stream>>>(Wp, wpb, 1048576);

  qkv_gemm<<<dim3(DMODEL / 128, MROWS / 128, 3), 256, 0, stream>>>(
      xb, wqb, wkb, wvb, bq, bk, bv, q_ws, k_ws, vt_ws);

  attn_fused<<<dim3(T_SEQ / 64, 2 * NHEAD), 256, 0, stream>>>(q_ws, k_ws, vt_ws, ao);

  out_gemm<<<dim3(DMODEL / 128, MROWS / 128), 256, 0, stream>>>(ao, wpb, bp, out);
}